// Round 3
// baseline (313.995 us; speedup 1.0000x reference)
//
#include <hip/hip_runtime.h>
#include <math.h>

// SSIM loss: 1 - mean(SSIM(x,y)), 11x11 separable gaussian, VALID padding.
// x,y: fp32 [16,3,512,512] -> 48 channels of 512x512; output map 502x502.
//
// Blur only {p=x+y, q=x-y, p^2, q^2} (4 blurs instead of 5):
//   P=blur(p), Q=blur(q), S2=blur(p^2), T2=blur(q^2)
//   lum num/den   = (P^2-Q^2+2C1)/(P^2+Q^2+2C1)
//   contrast n/d  = (S2-T2-(P^2-Q^2)+2C2)/(S2+T2-(P^2+Q^2)+2C2)
//
// R2 (resubmitted R3 after broker timeout): SEG_ROWS 32->16 (1536 blocks;
// R1 showed grid starvation: occ 15.7%, VALUBusy 43%), __fdividef epilogue,
// launch_bounds(256,4).

#define HH 512
#define WW 512
#define NCH 48
#define OUTD 502
#define SEGS 32
#define SEG_ROWS 16
#define ITERS 26            // SEG_ROWS + 10
#define NBLK (NCH * SEGS)   // 1536

#define TWO_C1 13.0050f     // 2*(0.01*255)^2
#define TWO_C2 117.0450f    // 2*(0.03*255)^2

struct GW { float g[11]; };

__global__ __launch_bounds__(256, 4)
void ssim_main(const float* __restrict__ x, const float* __restrict__ y,
               float* __restrict__ partial, GW gw) {
    const int tid = threadIdx.x;
    const int bid = blockIdx.x;
    const int ch  = bid >> 5;        // / SEGS
    const int seg = bid & (SEGS - 1);
    const int r0  = seg * SEG_ROWS;
    const int nrows = min(SEG_ROWS, OUTD - r0);

    int j = 2 * tid;
    const bool jvalid = (j < OUTD);
    if (!jvalid) j = 500;            // safe clamp; contribution masked below

    const size_t chbase = (size_t)ch * (HH * WW);
    const float* xb = x + chbase + j;
    const float* yb = y + chbase + j;

    // ring of horizontally-blurred rows: 4 quantities x 11 rows x 2 cols
    float rP[11][2], rQ[11][2], rS[11][2], rT[11][2];
    float acc = 0.0f;

    #pragma unroll
    for (int it = 0; it < ITERS; ++it) {
        const int s = it % 11;               // folds after full unroll
        const int r = min(r0 + it, HH - 1);  // wave-uniform
        const float2* xr = (const float2*)(xb + (size_t)r * WW);
        const float2* yr = (const float2*)(yb + (size_t)r * WW);

        float p[12], q[12];
        #pragma unroll
        for (int d = 0; d < 6; ++d) {
            float2 xv = xr[d];
            float2 yv = yr[d];
            p[2*d]   = xv.x + yv.x;  q[2*d]   = xv.x - yv.x;
            p[2*d+1] = xv.y + yv.y;  q[2*d+1] = xv.y - yv.y;
        }

        float hp0=0.f,hq0=0.f,hs0=0.f,ht0=0.f;
        float hp1=0.f,hq1=0.f,hs1=0.f,ht1=0.f;
        #pragma unroll
        for (int k = 0; k < 11; ++k) {
            const float w = gw.g[k];
            const float pk = p[k],   qk = q[k];
            const float pk1 = p[k+1], qk1 = q[k+1];
            hp0 = fmaf(w, pk,      hp0);  hq0 = fmaf(w, qk,      hq0);
            hs0 = fmaf(w, pk*pk,   hs0);  ht0 = fmaf(w, qk*qk,   ht0);
            hp1 = fmaf(w, pk1,     hp1);  hq1 = fmaf(w, qk1,     hq1);
            hs1 = fmaf(w, pk1*pk1, hs1);  ht1 = fmaf(w, qk1*qk1, ht1);
        }
        rP[s][0]=hp0; rP[s][1]=hp1;  rQ[s][0]=hq0; rQ[s][1]=hq1;
        rS[s][0]=hs0; rS[s][1]=hs1;  rT[s][0]=ht0; rT[s][1]=ht1;

        const int il = it - 10;      // local output row
        if (il >= 0 && il < nrows && jvalid) {
            float P0=0.f,Q0=0.f,S0=0.f,T0=0.f;
            float P1=0.f,Q1=0.f,S1=0.f,T1=0.f;
            #pragma unroll
            for (int k = 0; k < 11; ++k) {
                const int sl = (s + 1 + k) % 11;   // static after unroll
                const float w = gw.g[k];
                P0=fmaf(w,rP[sl][0],P0); Q0=fmaf(w,rQ[sl][0],Q0);
                S0=fmaf(w,rS[sl][0],S0); T0=fmaf(w,rT[sl][0],T0);
                P1=fmaf(w,rP[sl][1],P1); Q1=fmaf(w,rQ[sl][1],Q1);
                S1=fmaf(w,rS[sl][1],S1); T1=fmaf(w,rT[sl][1],T1);
            }
            // col 0
            {
                float A = P0*P0, B = Q0*Q0;
                float u1 = A - B, u2 = A + B;
                float ln_ = u1 + TWO_C1;
                float ld_ = u2 + TWO_C1;
                float cn_ = (S0 - T0) - u1 + TWO_C2;
                float cd_ = (S0 + T0) - u2 + TWO_C2;
                acc += __fdividef(ln_ * cn_, ld_ * cd_);
            }
            // col 1
            {
                float A = P1*P1, B = Q1*Q1;
                float u1 = A - B, u2 = A + B;
                float ln_ = u1 + TWO_C1;
                float ld_ = u2 + TWO_C1;
                float cn_ = (S1 - T1) - u1 + TWO_C2;
                float cd_ = (S1 + T1) - u2 + TWO_C2;
                acc += __fdividef(ln_ * cn_, ld_ * cd_);
            }
        }
    }

    // block reduction: wave shfl, then LDS across the 4 waves
    #pragma unroll
    for (int off = 32; off > 0; off >>= 1) acc += __shfl_down(acc, off);
    __shared__ float sh[4];
    const int wid  = tid >> 6;
    const int lane = tid & 63;
    if (lane == 0) sh[wid] = acc;
    __syncthreads();
    if (tid == 0) partial[bid] = sh[0] + sh[1] + sh[2] + sh[3];
}

__global__ void ssim_reduce(const float* __restrict__ partial,
                            float* __restrict__ out) {
    double s = 0.0;
    for (int i = threadIdx.x; i < NBLK; i += 256) s += (double)partial[i];
    #pragma unroll
    for (int off = 32; off > 0; off >>= 1) s += __shfl_down(s, off);
    __shared__ double sh[4];
    const int wid  = threadIdx.x >> 6;
    const int lane = threadIdx.x & 63;
    if (lane == 0) sh[wid] = s;
    __syncthreads();
    if (threadIdx.x == 0) {
        double tot = sh[0] + sh[1] + sh[2] + sh[3];
        double cnt = (double)NCH * (double)OUTD * (double)OUTD;
        out[0] = (float)(1.0 - tot / cnt);
    }
}

extern "C" void kernel_launch(void* const* d_in, const int* in_sizes, int n_in,
                              void* d_out, int out_size, void* d_ws, size_t ws_size,
                              hipStream_t stream) {
    const float* x = (const float*)d_in[0];
    const float* y = (const float*)d_in[1];
    // d_in[2] = epoch, unused (dead code in reference)
    float* out = (float*)d_out;
    float* ws  = (float*)d_ws;   // NBLK floats of partial sums

    GW gw;
    {
        double v[11], sum = 0.0;
        for (int k = 0; k < 11; ++k) {
            double c = (double)(k - 5);
            v[k] = exp(-(c * c) / 4.5);   // 2*sigma^2 = 4.5
            sum += v[k];
        }
        for (int k = 0; k < 11; ++k) gw.g[k] = (float)(v[k] / sum);
    }

    hipLaunchKernelGGL(ssim_main, dim3(NBLK), dim3(256), 0, stream, x, y, ws, gw);
    hipLaunchKernelGGL(ssim_reduce, dim3(1), dim3(256), 0, stream, ws, out);
}

// Round 6
// 188.440 us; speedup vs baseline: 1.6663x; 1.6663x over previous
//
#include <hip/hip_runtime.h>
#include <math.h>

// SSIM loss: 1 - mean(SSIM(x,y)), 11x11 separable gaussian, VALID padding.
// x,y: fp32 [16,3,512,512] -> 48 channels of 512x512; output map 502x502.
//
// Blur only {p=x+y, q=x-y, p^2, q^2} (4 blurs instead of 5):
//   P=blur(p), Q=blur(q), S2=blur(p^2), T2=blur(q^2)
//   lum num/den   = (P^2-Q^2+2C1)/(P^2+Q^2+2C1)
//   contrast n/d  = (S2-T2-(P^2-Q^2)+2C2)/(S2+T2-(P^2+Q^2)+2C2)
//
// R4 (resubmitted R6; broker timeouts R4/R5): revert launch_bounds to (256,2).
// R3's (256,4) clamped VGPR 88->64 and spilled the 88-float ring to scratch
// (WRITE_SIZE 24KB->84MB, VALUBusy 43->23%, dur 111->233us). Keep SEGS=32
// (1536 blocks) + __fdividef. 88 VGPR -> 4 blocks/CU; demand 6/CU.

#define HH 512
#define WW 512
#define NCH 48
#define OUTD 502
#define SEGS 32
#define SEG_ROWS 16
#define ITERS 26            // SEG_ROWS + 10
#define NBLK (NCH * SEGS)   // 1536

#define TWO_C1 13.0050f     // 2*(0.01*255)^2
#define TWO_C2 117.0450f    // 2*(0.03*255)^2

struct GW { float g[11]; };

__global__ __launch_bounds__(256, 2)
void ssim_main(const float* __restrict__ x, const float* __restrict__ y,
               float* __restrict__ partial, GW gw) {
    const int tid = threadIdx.x;
    const int bid = blockIdx.x;
    const int ch  = bid >> 5;        // / SEGS
    const int seg = bid & (SEGS - 1);
    const int r0  = seg * SEG_ROWS;
    const int nrows = min(SEG_ROWS, OUTD - r0);

    int j = 2 * tid;
    const bool jvalid = (j < OUTD);
    if (!jvalid) j = 500;            // safe clamp; contribution masked below

    const size_t chbase = (size_t)ch * (HH * WW);
    const float* xb = x + chbase + j;
    const float* yb = y + chbase + j;

    // ring of horizontally-blurred rows: 4 quantities x 11 rows x 2 cols
    float rP[11][2], rQ[11][2], rS[11][2], rT[11][2];
    float acc = 0.0f;

    #pragma unroll
    for (int it = 0; it < ITERS; ++it) {
        const int s = it % 11;               // folds after full unroll
        const int r = min(r0 + it, HH - 1);  // wave-uniform
        const float2* xr = (const float2*)(xb + (size_t)r * WW);
        const float2* yr = (const float2*)(yb + (size_t)r * WW);

        float p[12], q[12];
        #pragma unroll
        for (int d = 0; d < 6; ++d) {
            float2 xv = xr[d];
            float2 yv = yr[d];
            p[2*d]   = xv.x + yv.x;  q[2*d]   = xv.x - yv.x;
            p[2*d+1] = xv.y + yv.y;  q[2*d+1] = xv.y - yv.y;
        }

        float hp0=0.f,hq0=0.f,hs0=0.f,ht0=0.f;
        float hp1=0.f,hq1=0.f,hs1=0.f,ht1=0.f;
        #pragma unroll
        for (int k = 0; k < 11; ++k) {
            const float w = gw.g[k];
            const float pk = p[k],   qk = q[k];
            const float pk1 = p[k+1], qk1 = q[k+1];
            hp0 = fmaf(w, pk,      hp0);  hq0 = fmaf(w, qk,      hq0);
            hs0 = fmaf(w, pk*pk,   hs0);  ht0 = fmaf(w, qk*qk,   ht0);
            hp1 = fmaf(w, pk1,     hp1);  hq1 = fmaf(w, qk1,     hq1);
            hs1 = fmaf(w, pk1*pk1, hs1);  ht1 = fmaf(w, qk1*qk1, ht1);
        }
        rP[s][0]=hp0; rP[s][1]=hp1;  rQ[s][0]=hq0; rQ[s][1]=hq1;
        rS[s][0]=hs0; rS[s][1]=hs1;  rT[s][0]=ht0; rT[s][1]=ht1;

        const int il = it - 10;      // local output row
        if (il >= 0 && il < nrows && jvalid) {
            float P0=0.f,Q0=0.f,S0=0.f,T0=0.f;
            float P1=0.f,Q1=0.f,S1=0.f,T1=0.f;
            #pragma unroll
            for (int k = 0; k < 11; ++k) {
                const int sl = (s + 1 + k) % 11;   // static after unroll
                const float w = gw.g[k];
                P0=fmaf(w,rP[sl][0],P0); Q0=fmaf(w,rQ[sl][0],Q0);
                S0=fmaf(w,rS[sl][0],S0); T0=fmaf(w,rT[sl][0],T0);
                P1=fmaf(w,rP[sl][1],P1); Q1=fmaf(w,rQ[sl][1],Q1);
                S1=fmaf(w,rS[sl][1],S1); T1=fmaf(w,rT[sl][1],T1);
            }
            // col 0
            {
                float A = P0*P0, B = Q0*Q0;
                float u1 = A - B, u2 = A + B;
                float ln_ = u1 + TWO_C1;
                float ld_ = u2 + TWO_C1;
                float cn_ = (S0 - T0) - u1 + TWO_C2;
                float cd_ = (S0 + T0) - u2 + TWO_C2;
                acc += __fdividef(ln_ * cn_, ld_ * cd_);
            }
            // col 1
            {
                float A = P1*P1, B = Q1*Q1;
                float u1 = A - B, u2 = A + B;
                float ln_ = u1 + TWO_C1;
                float ld_ = u2 + TWO_C1;
                float cn_ = (S1 - T1) - u1 + TWO_C2;
                float cd_ = (S1 + T1) - u2 + TWO_C2;
                acc += __fdividef(ln_ * cn_, ld_ * cd_);
            }
        }
    }

    // block reduction: wave shfl, then LDS across the 4 waves
    #pragma unroll
    for (int off = 32; off > 0; off >>= 1) acc += __shfl_down(acc, off);
    __shared__ float sh[4];
    const int wid  = tid >> 6;
    const int lane = tid & 63;
    if (lane == 0) sh[wid] = acc;
    __syncthreads();
    if (tid == 0) partial[bid] = sh[0] + sh[1] + sh[2] + sh[3];
}

__global__ void ssim_reduce(const float* __restrict__ partial,
                            float* __restrict__ out) {
    double s = 0.0;
    for (int i = threadIdx.x; i < NBLK; i += 256) s += (double)partial[i];
    #pragma unroll
    for (int off = 32; off > 0; off >>= 1) s += __shfl_down(s, off);
    __shared__ double sh[4];
    const int wid  = threadIdx.x >> 6;
    const int lane = threadIdx.x & 63;
    if (lane == 0) sh[wid] = s;
    __syncthreads();
    if (threadIdx.x == 0) {
        double tot = sh[0] + sh[1] + sh[2] + sh[3];
        double cnt = (double)NCH * (double)OUTD * (double)OUTD;
        out[0] = (float)(1.0 - tot / cnt);
    }
}

extern "C" void kernel_launch(void* const* d_in, const int* in_sizes, int n_in,
                              void* d_out, int out_size, void* d_ws, size_t ws_size,
                              hipStream_t stream) {
    const float* x = (const float*)d_in[0];
    const float* y = (const float*)d_in[1];
    // d_in[2] = epoch, unused (dead code in reference)
    float* out = (float*)d_out;
    float* ws  = (float*)d_ws;   // NBLK floats of partial sums

    GW gw;
    {
        double v[11], sum = 0.0;
        for (int k = 0; k < 11; ++k) {
            double c = (double)(k - 5);
            v[k] = exp(-(c * c) / 4.5);   // 2*sigma^2 = 4.5
            sum += v[k];
        }
        for (int k = 0; k < 11; ++k) gw.g[k] = (float)(v[k] / sum);
    }

    hipLaunchKernelGGL(ssim_main, dim3(NBLK), dim3(256), 0, stream, x, y, ws, gw);
    hipLaunchKernelGGL(ssim_reduce, dim3(1), dim3(256), 0, stream, ws, out);
}

// Round 7
// 174.506 us; speedup vs baseline: 1.7993x; 1.0798x over previous
//
#include <hip/hip_runtime.h>
#include <math.h>

// SSIM loss: 1 - mean(SSIM(x,y)), 11x11 separable gaussian, VALID padding.
// x,y: fp32 [16,3,512,512] -> 48 channels of 512x512; output map 502x502.
//
// Blur only {p=x+y, q=x-y, p^2, q^2} (4 blurs instead of 5).
//
// R7: LDS row-staging of p,q. R6 diagnosis: 6x L1 redundancy (96B/thread-row
// direct loads for 4KB unique/block-row) capped VALUBusy at ~55%. Now waves
// 0-1 stage p, waves 2-3 stage q (1 float4-pair load + ds_write_b128 each);
// compute reads 12 float2 windows from LDS (2-way bank alias = free).
// T14 split: next-row loads issued before current-row compute; ds_write
// after; 1 barrier/row, double-buffered LDS (WAR-safe).

#define HH 512
#define WW 512
#define NCH 48
#define OUTD 502
#define SEGS 32
#define SEG_ROWS 16
#define ITERS 26            // SEG_ROWS + 10
#define NBLK (NCH * SEGS)   // 1536

#define TWO_C1 13.0050f     // 2*(0.01*255)^2
#define TWO_C2 117.0450f    // 2*(0.03*255)^2

struct GW { float g[11]; };

__global__ __launch_bounds__(256, 2)
void ssim_main(const float* __restrict__ x, const float* __restrict__ y,
               float* __restrict__ partial, GW gw) {
    __shared__ float lds[2][2][WW];   // [parity][0=p,1=q][col]  (8 KB)

    const int tid = threadIdx.x;
    const int bid = blockIdx.x;
    const int ch  = bid >> 5;        // / SEGS
    const int seg = bid & (SEGS - 1);
    const int r0  = seg * SEG_ROWS;
    const int nrows = min(SEG_ROWS, OUTD - r0);

    int j = 2 * tid;
    const bool jvalid = (j < OUTD);
    if (!jvalid) j = 500;            // clamp; contribution masked below
    const int tcol = j >> 1;         // float2 index of window start

    const size_t chbase = (size_t)ch * (HH * WW);
    const float* xc = x + chbase;
    const float* yc = y + chbase;

    const int isq   = (tid >> 7) & 1;   // waves 0-1 stage p, waves 2-3 stage q
    const int chunk = tid & 127;        // float4 chunk (cols 4*chunk..+3)

    // ring of horizontally-blurred rows: 4 quantities x 11 rows x 2 cols
    float rP[11][2], rQ[11][2], rS[11][2], rT[11][2];
    float acc = 0.0f;

    // prologue: stage row r0 into parity 0
    {
        float4 xv = ((const float4*)(xc + (size_t)r0 * WW))[chunk];
        float4 yv = ((const float4*)(yc + (size_t)r0 * WW))[chunk];
        float4 w;
        if (isq == 0) { w.x=xv.x+yv.x; w.y=xv.y+yv.y; w.z=xv.z+yv.z; w.w=xv.w+yv.w; }
        else          { w.x=xv.x-yv.x; w.y=xv.y-yv.y; w.z=xv.z-yv.z; w.w=xv.w-yv.w; }
        ((float4*)&lds[0][isq][0])[chunk] = w;
    }
    __syncthreads();

    #pragma unroll
    for (int it = 0; it < ITERS; ++it) {
        const int par = it & 1;
        const int s   = it % 11;         // folds after full unroll

        // T14: issue next row's global loads before compute
        float4 xv, yv;
        if (it < ITERS - 1) {
            const int rn = min(r0 + it + 1, HH - 1);   // wave-uniform
            xv = ((const float4*)(xc + (size_t)rn * WW))[chunk];
            yv = ((const float4*)(yc + (size_t)rn * WW))[chunk];
        }

        // read 12-col p,q windows from LDS
        float p[12], q[12];
        {
            const float2* pb = (const float2*)&lds[par][0][0];
            const float2* qb = (const float2*)&lds[par][1][0];
            #pragma unroll
            for (int k2 = 0; k2 < 6; ++k2) {
                float2 pv = pb[tcol + k2];
                float2 qv = qb[tcol + k2];
                p[2*k2] = pv.x; p[2*k2+1] = pv.y;
                q[2*k2] = qv.x; q[2*k2+1] = qv.y;
            }
        }

        // h-pass: 4 quantities x 2 cols
        float hp0=0.f,hq0=0.f,hs0=0.f,ht0=0.f;
        float hp1=0.f,hq1=0.f,hs1=0.f,ht1=0.f;
        #pragma unroll
        for (int k = 0; k < 11; ++k) {
            const float w = gw.g[k];
            const float pk = p[k],   qk = q[k];
            const float pk1 = p[k+1], qk1 = q[k+1];
            hp0 = fmaf(w, pk,      hp0);  hq0 = fmaf(w, qk,      hq0);
            hs0 = fmaf(w, pk*pk,   hs0);  ht0 = fmaf(w, qk*qk,   ht0);
            hp1 = fmaf(w, pk1,     hp1);  hq1 = fmaf(w, qk1,     hq1);
            hs1 = fmaf(w, pk1*pk1, hs1);  ht1 = fmaf(w, qk1*qk1, ht1);
        }
        rP[s][0]=hp0; rP[s][1]=hp1;  rQ[s][0]=hq0; rQ[s][1]=hq1;
        rS[s][0]=hs0; rS[s][1]=hs1;  rT[s][0]=ht0; rT[s][1]=ht1;

        // v-pass + epilogue
        const int il = it - 10;
        if (il >= 0 && il < nrows && jvalid) {
            float P0=0.f,Q0=0.f,S0=0.f,T0=0.f;
            float P1=0.f,Q1=0.f,S1=0.f,T1=0.f;
            #pragma unroll
            for (int k = 0; k < 11; ++k) {
                const int sl = (s + 1 + k) % 11;   // static after unroll
                const float w = gw.g[k];
                P0=fmaf(w,rP[sl][0],P0); Q0=fmaf(w,rQ[sl][0],Q0);
                S0=fmaf(w,rS[sl][0],S0); T0=fmaf(w,rT[sl][0],T0);
                P1=fmaf(w,rP[sl][1],P1); Q1=fmaf(w,rQ[sl][1],Q1);
                S1=fmaf(w,rS[sl][1],S1); T1=fmaf(w,rT[sl][1],T1);
            }
            {
                float A = P0*P0, B = Q0*Q0;
                float u1 = A - B, u2 = A + B;
                float ln_ = u1 + TWO_C1;
                float ld_ = u2 + TWO_C1;
                float cn_ = (S0 - T0) - u1 + TWO_C2;
                float cd_ = (S0 + T0) - u2 + TWO_C2;
                acc += __fdividef(ln_ * cn_, ld_ * cd_);
            }
            {
                float A = P1*P1, B = Q1*Q1;
                float u1 = A - B, u2 = A + B;
                float ln_ = u1 + TWO_C1;
                float ld_ = u2 + TWO_C1;
                float cn_ = (S1 - T1) - u1 + TWO_C2;
                float cd_ = (S1 + T1) - u2 + TWO_C2;
                acc += __fdividef(ln_ * cn_, ld_ * cd_);
            }
        }

        // stage next row into the other parity buffer.
        // WAR-safe: all waves' reads of lds[par^1] happened in iter it-1,
        // before the barrier at the end of it-1.
        if (it < ITERS - 1) {
            float4 w;
            if (isq == 0) { w.x=xv.x+yv.x; w.y=xv.y+yv.y; w.z=xv.z+yv.z; w.w=xv.w+yv.w; }
            else          { w.x=xv.x-yv.x; w.y=xv.y-yv.y; w.z=xv.z-yv.z; w.w=xv.w-yv.w; }
            ((float4*)&lds[par^1][isq][0])[chunk] = w;
        }
        __syncthreads();
    }

    // block reduction: wave shfl, then LDS across the 4 waves
    #pragma unroll
    for (int off = 32; off > 0; off >>= 1) acc += __shfl_down(acc, off);
    __shared__ float sh[4];
    const int wid  = tid >> 6;
    const int lane = tid & 63;
    if (lane == 0) sh[wid] = acc;
    __syncthreads();
    if (tid == 0) partial[bid] = sh[0] + sh[1] + sh[2] + sh[3];
}

__global__ void ssim_reduce(const float* __restrict__ partial,
                            float* __restrict__ out) {
    double s = 0.0;
    for (int i = threadIdx.x; i < NBLK; i += 256) s += (double)partial[i];
    #pragma unroll
    for (int off = 32; off > 0; off >>= 1) s += __shfl_down(s, off);
    __shared__ double sh[4];
    const int wid  = threadIdx.x >> 6;
    const int lane = threadIdx.x & 63;
    if (lane == 0) sh[wid] = s;
    __syncthreads();
    if (threadIdx.x == 0) {
        double tot = sh[0] + sh[1] + sh[2] + sh[3];
        double cnt = (double)NCH * (double)OUTD * (double)OUTD;
        out[0] = (float)(1.0 - tot / cnt);
    }
}

extern "C" void kernel_launch(void* const* d_in, const int* in_sizes, int n_in,
                              void* d_out, int out_size, void* d_ws, size_t ws_size,
                              hipStream_t stream) {
    const float* x = (const float*)d_in[0];
    const float* y = (const float*)d_in[1];
    // d_in[2] = epoch, unused (dead code in reference)
    float* out = (float*)d_out;
    float* ws  = (float*)d_ws;   // NBLK floats of partial sums

    GW gw;
    {
        double v[11], sum = 0.0;
        for (int k = 0; k < 11; ++k) {
            double c = (double)(k - 5);
            v[k] = exp(-(c * c) / 4.5);   // 2*sigma^2 = 4.5
            sum += v[k];
        }
        for (int k = 0; k < 11; ++k) gw.g[k] = (float)(v[k] / sum);
    }

    hipLaunchKernelGGL(ssim_main, dim3(NBLK), dim3(256), 0, stream, x, y, ws, gw);
    hipLaunchKernelGGL(ssim_reduce, dim3(1), dim3(256), 0, stream, ws, out);
}

// Round 11
// 169.257 us; speedup vs baseline: 1.8551x; 1.0310x over previous
//
#include <hip/hip_runtime.h>
#include <math.h>

// SSIM loss: 1 - mean(SSIM(x,y)), 11x11 separable gaussian, VALID padding.
// x,y: fp32 [16,3,512,512] -> 48 channels of 512x512; output map 502x502.
//
// Blur only {p=x+y, q=x-y, p^2, q^2} (4 blurs instead of 5).
//
// R8 (resubmitted R11; broker timeouts R8/R9/R10; from R7 counters: 88us,
// VALUBusy 62%, 5.7M LDS conflicts, VGPR 120):
//  - SEG_ROWS 16->23, ITERS 33=3*11: halo 1.625x->1.43x (-13% row work),
//    ring phase folds per-11 so Phase B outer loop can stay rolled (x2)
//    with static ring indices -> ~2.4x smaller code body (I-cache).
//  - staging de-dup: each thread loads float2 of x,y (4KB unique/row) and
//    writes both p,q (R7 loaded every float4 twice across wave-pairs).
//  - epilogue: single __fdividef for both columns.

#define HH 512
#define WW 512
#define NCH 48
#define OUTD 502
#define SEGS 22
#define SEG_ROWS 23
#define ITERS 33            // 3*11 = SEG_ROWS + 10
#define NBLK (NCH * SEGS)   // 1056

#define TWO_C1 13.0050f     // 2*(0.01*255)^2
#define TWO_C2 117.0450f    // 2*(0.03*255)^2

struct GW { float g[11]; };

// h-pass: 11-tap blur of p, q, p^2, q^2 for 2 cols -> ring slot UU
#define HCHAIN(UU)                                                         \
    {                                                                      \
        float hp0=0.f,hq0=0.f,hs0=0.f,ht0=0.f;                             \
        float hp1=0.f,hq1=0.f,hs1=0.f,ht1=0.f;                             \
        _Pragma("unroll")                                                  \
        for (int k = 0; k < 11; ++k) {                                     \
            const float w = gw.g[k];                                       \
            const float pk = p[k],   qk = q[k];                            \
            const float pk1 = p[k+1], qk1 = q[k+1];                        \
            hp0 = fmaf(w, pk,      hp0);  hq0 = fmaf(w, qk,      hq0);     \
            hs0 = fmaf(w, pk*pk,   hs0);  ht0 = fmaf(w, qk*qk,   ht0);     \
            hp1 = fmaf(w, pk1,     hp1);  hq1 = fmaf(w, qk1,     hq1);     \
            hs1 = fmaf(w, pk1*pk1, hs1);  ht1 = fmaf(w, qk1*qk1, ht1);     \
        }                                                                  \
        rP[UU][0]=hp0; rP[UU][1]=hp1;  rQ[UU][0]=hq0; rQ[UU][1]=hq1;       \
        rS[UU][0]=hs0; rS[UU][1]=hs1;  rT[UU][0]=ht0; rT[UU][1]=ht1;       \
    }

// read 12-col p,q windows from LDS buffer PARX
#define READ_WINDOW(PARX)                                                  \
    float p[12], q[12];                                                    \
    {                                                                      \
        const float2* pb = (const float2*)&lds[PARX][0][0];                \
        const float2* qb = (const float2*)&lds[PARX][1][0];                \
        _Pragma("unroll")                                                  \
        for (int k2 = 0; k2 < 6; ++k2) {                                   \
            float2 pv = pb[tcol + k2];                                     \
            float2 qv = qb[tcol + k2];                                     \
            p[2*k2] = pv.x; p[2*k2+1] = pv.y;                              \
            q[2*k2] = qv.x; q[2*k2+1] = qv.y;                              \
        }                                                                  \
    }

// write staged p,q row (from prefetched nxv,nyv) into buffer PARX
#define STAGE_WRITE(PARX)                                                  \
    {                                                                      \
        float2 pw, qw;                                                     \
        pw.x = nxv.x + nyv.x;  pw.y = nxv.y + nyv.y;                       \
        qw.x = nxv.x - nyv.x;  qw.y = nxv.y - nyv.y;                       \
        ((float2*)&lds[PARX][0][0])[tid] = pw;                             \
        ((float2*)&lds[PARX][1][0])[tid] = qw;                             \
    }

// v-pass (ring shift base UU+1) + epilogue with single divide
#define VEPI(UU)                                                           \
    {                                                                      \
        float P0=0.f,Q0=0.f,Sv0=0.f,Tv0=0.f;                               \
        float P1=0.f,Q1=0.f,Sv1=0.f,Tv1=0.f;                               \
        _Pragma("unroll")                                                  \
        for (int k = 0; k < 11; ++k) {                                     \
            const int sl = ((UU) + 1 + k) % 11;                            \
            const float w = gw.g[k];                                       \
            P0=fmaf(w,rP[sl][0],P0);   Q0=fmaf(w,rQ[sl][0],Q0);            \
            Sv0=fmaf(w,rS[sl][0],Sv0); Tv0=fmaf(w,rT[sl][0],Tv0);          \
            P1=fmaf(w,rP[sl][1],P1);   Q1=fmaf(w,rQ[sl][1],Q1);            \
            Sv1=fmaf(w,rS[sl][1],Sv1); Tv1=fmaf(w,rT[sl][1],Tv1);          \
        }                                                                  \
        float A0=P0*P0, B0=Q0*Q0;                                          \
        float u10=A0-B0, u20=A0+B0;                                        \
        float ln0=u10+TWO_C1, ld0=u20+TWO_C1;                              \
        float cn0=(Sv0-Tv0)-u10+TWO_C2, cd0=(Sv0+Tv0)-u20+TWO_C2;          \
        float A1=P1*P1, B1=Q1*Q1;                                          \
        float u11=A1-B1, u21=A1+B1;                                        \
        float ln1=u11+TWO_C1, ld1=u21+TWO_C1;                              \
        float cn1=(Sv1-Tv1)-u11+TWO_C2, cd1=(Sv1+Tv1)-u21+TWO_C2;          \
        float n0=ln0*cn0, d0=ld0*cd0;                                      \
        float n1=ln1*cn1, d1=ld1*cd1;                                      \
        float num=fmaf(n0,d1,n1*d0), den=d0*d1;                            \
        float val=__fdividef(num,den);                                     \
        if (jvalid) acc += val;                                            \
    }

__global__ __launch_bounds__(256, 2)
void ssim_main(const float* __restrict__ x, const float* __restrict__ y,
               float* __restrict__ partial, GW gw) {
    __shared__ float lds[2][2][WW];   // [parity][0=p,1=q][col]  (8 KB)

    const int tid = threadIdx.x;
    const int bid = blockIdx.x;
    const int ch  = bid / SEGS;
    const int seg = bid - ch * SEGS;
    const int r0  = seg * SEG_ROWS;
    const int nrows = min(SEG_ROWS, OUTD - r0);

    const bool jvalid = (tid < 251);        // 2*tid < 502
    const int tcol = jvalid ? tid : 250;    // float2 index of window start

    const size_t chbase = (size_t)ch * (HH * WW);
    const float* xc = x + chbase;
    const float* yc = y + chbase;

    // ring of horizontally-blurred rows: 4 quantities x 11 rows x 2 cols
    float rP[11][2], rQ[11][2], rS[11][2], rT[11][2];
    float acc = 0.0f;

    // prologue: stage row r0 into parity 0
    {
        float2 nxv = ((const float2*)(xc + (size_t)r0 * WW))[tid];
        float2 nyv = ((const float2*)(yc + (size_t)r0 * WW))[tid];
        STAGE_WRITE(0)
    }
    __syncthreads();

    // Phase A: it = 0..10 — fill ring; first output at u == 10
    #pragma unroll
    for (int u = 0; u < 11; ++u) {
        const int par = u & 1;
        // T14: prefetch next row (it+1 <= 11 < ITERS always)
        float2 nxv, nyv;
        {
            const int rn = r0 + u + 1;            // <= 483+11 < 512
            nxv = ((const float2*)(xc + (size_t)rn * WW))[tid];
            nyv = ((const float2*)(yc + (size_t)rn * WW))[tid];
        }
        READ_WINDOW(par)
        HCHAIN(u)
        if (u == 10) {
            VEPI(10)        // il = 0, always < nrows
        }
        STAGE_WRITE(par ^ 1)
        __syncthreads();
    }

    // Phase B: blk = 1,2 — steady state, ring indices static via inner unroll
    #pragma unroll 1
    for (int blk = 1; blk < 3; ++blk) {
        #pragma unroll
        for (int u = 0; u < 11; ++u) {
            const int it  = 11 * blk + u;
            const int par = (blk + u) & 1;
            const bool more = (it < ITERS - 1);
            float2 nxv, nyv;
            if (more) {
                const int rn = min(r0 + it + 1, HH - 1);   // wave-uniform
                nxv = ((const float2*)(xc + (size_t)rn * WW))[tid];
                nyv = ((const float2*)(yc + (size_t)rn * WW))[tid];
            }
            READ_WINDOW(par)
            HCHAIN(u)
            const int il = it - 10;          // 1..23
            if (il < nrows) {                // wave-uniform
                VEPI(u)
            }
            if (more) {
                STAGE_WRITE(par ^ 1)
            }
            __syncthreads();
        }
    }

    // block reduction: wave shfl, then LDS across the 4 waves
    #pragma unroll
    for (int off = 32; off > 0; off >>= 1) acc += __shfl_down(acc, off);
    __shared__ float sh[4];
    const int wid  = tid >> 6;
    const int lane = tid & 63;
    if (lane == 0) sh[wid] = acc;
    __syncthreads();
    if (tid == 0) partial[bid] = sh[0] + sh[1] + sh[2] + sh[3];
}

__global__ void ssim_reduce(const float* __restrict__ partial,
                            float* __restrict__ out) {
    double s = 0.0;
    for (int i = threadIdx.x; i < NBLK; i += 256) s += (double)partial[i];
    #pragma unroll
    for (int off = 32; off > 0; off >>= 1) s += __shfl_down(s, off);
    __shared__ double sh[4];
    const int wid  = threadIdx.x >> 6;
    const int lane = threadIdx.x & 63;
    if (lane == 0) sh[wid] = s;
    __syncthreads();
    if (threadIdx.x == 0) {
        double tot = sh[0] + sh[1] + sh[2] + sh[3];
        double cnt = (double)NCH * (double)OUTD * (double)OUTD;
        out[0] = (float)(1.0 - tot / cnt);
    }
}

extern "C" void kernel_launch(void* const* d_in, const int* in_sizes, int n_in,
                              void* d_out, int out_size, void* d_ws, size_t ws_size,
                              hipStream_t stream) {
    const float* x = (const float*)d_in[0];
    const float* y = (const float*)d_in[1];
    // d_in[2] = epoch, unused (dead code in reference)
    float* out = (float*)d_out;
    float* ws  = (float*)d_ws;   // NBLK floats of partial sums

    GW gw;
    {
        double v[11], sum = 0.0;
        for (int k = 0; k < 11; ++k) {
            double c = (double)(k - 5);
            v[k] = exp(-(c * c) / 4.5);   // 2*sigma^2 = 4.5
            sum += v[k];
        }
        for (int k = 0; k < 11; ++k) gw.g[k] = (float)(v[k] / sum);
    }

    hipLaunchKernelGGL(ssim_main, dim3(NBLK), dim3(256), 0, stream, x, y, ws, gw);
    hipLaunchKernelGGL(ssim_reduce, dim3(1), dim3(256), 0, stream, ws, out);
}